// Round 1
// baseline (234.140 us; speedup 1.0000x reference)
//
#include <hip/hip_runtime.h>

typedef unsigned short u16;
typedef __attribute__((ext_vector_type(8))) short short8;
typedef __attribute__((ext_vector_type(4))) float f32x4;

// ---------- helpers ----------

__device__ __forceinline__ u16 f2bf(float f) {
  unsigned u = __builtin_bit_cast(unsigned, f);
  u += 0x7fffu + ((u >> 16) & 1u);   // RNE
  return (u16)(u >> 16);
}

__device__ __forceinline__ void gload16(const void* g, void* l) {
  __builtin_amdgcn_global_load_lds(
      (const __attribute__((address_space(1))) unsigned*)g,
      (__attribute__((address_space(3))) unsigned*)l, 16, 0, 0);
}

// ================================================================
// 256x128 8-phase-style GEMM core (K=1024 fixed), 512 threads / 8 waves.
// Waves 4(M)x2(N), each owns 64x64 -> acc[4][4].
// LDS: 3 K-tile buffers (A 256x64, B 128x64 bf16, 16B-chunk XOR swizzle),
// prefetch distance 2 tiles, counted s_waitcnt vmcnt(6) (never 0 in loop).
// Per K-tile: 2 phases, each {ds_read | stage 3 gloads | bar | lgkm0 |
// setprio(1) 16xMFMA setprio(0) | bar}.  (T2+T3+T4+T5 per learn_hip m201)
// ================================================================

#define QTILE(CUR, NXT, DOSTAGE, VM)                                         \
  {                                                                          \
    char* cA = sA0 + (CUR) * 32768;                                          \
    char* cB = sB0 + (CUR) * 16384;                                          \
    short8 bf[2][4], af[2][2];                                               \
    /* phase 0: B all frags (both kk) + A m-frags 0,1 */                     \
    _Pragma("unroll") for (int kk = 0; kk < 2; ++kk)                         \
      _Pragma("unroll") for (int j = 0; j < 4; ++j) {                        \
        const int rn = wc + j * 16 + l16;                                    \
        bf[kk][j] = *(const short8*)(cB + rn * 128 + (((kk << 2) + quad) ^ (rn & 7)) * 16); \
      }                                                                      \
    _Pragma("unroll") for (int kk = 0; kk < 2; ++kk)                         \
      _Pragma("unroll") for (int i = 0; i < 2; ++i) {                        \
        const int rm = wr + i * 16 + l16;                                    \
        af[kk][i] = *(const short8*)(cA + rm * 128 + (((kk << 2) + quad) ^ (rm & 7)) * 16); \
      }                                                                      \
    if (DOSTAGE) {                                                           \
      char* dA = sA0 + (NXT) * 32768;                                        \
      _Pragma("unroll") for (int j = 0; j < 3; ++j) { gload16(ga[j], dA + la[j]); ga[j] += 64; } \
    }                                                                        \
    asm volatile("" ::: "memory");                                           \
    __builtin_amdgcn_s_barrier();                                            \
    asm volatile("s_waitcnt lgkmcnt(0)" ::: "memory");                       \
    __builtin_amdgcn_sched_barrier(0);                                       \
    __builtin_amdgcn_s_setprio(1);                                           \
    _Pragma("unroll") for (int kk = 0; kk < 2; ++kk)                         \
      _Pragma("unroll") for (int i = 0; i < 2; ++i)                          \
        _Pragma("unroll") for (int j = 0; j < 4; ++j)                        \
          acc[i][j] = __builtin_amdgcn_mfma_f32_16x16x32_bf16(af[kk][i], bf[kk][j], acc[i][j], 0, 0, 0); \
    __builtin_amdgcn_s_setprio(0);                                           \
    asm volatile("" ::: "memory");                                           \
    __builtin_amdgcn_s_barrier();                                            \
    asm volatile("" ::: "memory");                                           \
    /* phase 1: A m-frags 2,3 (B held in regs) */                            \
    _Pragma("unroll") for (int kk = 0; kk < 2; ++kk)                         \
      _Pragma("unroll") for (int i = 0; i < 2; ++i) {                        \
        const int rm = wr + 32 + i * 16 + l16;                               \
        af[kk][i] = *(const short8*)(cA + rm * 128 + (((kk << 2) + quad) ^ (rm & 7)) * 16); \
      }                                                                      \
    if (DOSTAGE) {                                                           \
      char* dA = sA0 + (NXT) * 32768;                                        \
      char* dB = sB0 + (NXT) * 16384;                                        \
      gload16(ga[3], dA + la[3]); ga[3] += 64;                               \
      _Pragma("unroll") for (int j = 0; j < 2; ++j) { gload16(gb[j], dB + lb[j]); gb[j] += 64; } \
    }                                                                        \
    asm volatile("s_waitcnt vmcnt(" #VM ")" ::: "memory");                   \
    asm volatile("" ::: "memory");                                           \
    __builtin_amdgcn_s_barrier();                                            \
    asm volatile("s_waitcnt lgkmcnt(0)" ::: "memory");                       \
    __builtin_amdgcn_sched_barrier(0);                                       \
    __builtin_amdgcn_s_setprio(1);                                           \
    _Pragma("unroll") for (int kk = 0; kk < 2; ++kk)                         \
      _Pragma("unroll") for (int i = 0; i < 2; ++i)                          \
        _Pragma("unroll") for (int j = 0; j < 4; ++j)                        \
          acc[2 + i][j] = __builtin_amdgcn_mfma_f32_16x16x32_bf16(af[kk][i], bf[kk][j], acc[2 + i][j], 0, 0, 0); \
    __builtin_amdgcn_s_setprio(0);                                           \
    asm volatile("" ::: "memory");                                           \
    __builtin_amdgcn_s_barrier();                                            \
    asm volatile("" ::: "memory");                                           \
  }

__device__ __forceinline__ void gemm_256x128(
    const u16* __restrict__ A, const u16* __restrict__ B,
    int m0, int n0, char* smem, f32x4 acc[4][4])
{
  const int tid  = threadIdx.x;          // 0..511
  const int lane = tid & 63;
  const int quad = lane >> 4;
  const int l16  = lane & 15;
  const int wave = tid >> 6;             // 0..7
  const int wr   = (wave >> 1) << 6;     // 0,64,128,192
  const int wc   = (wave & 1) << 6;      // 0,64

  // staging sources (pre-swizzled global addr, linear LDS dest)
  const u16* ga[4]; int la[4];
  const u16* gb[2]; int lb[2];
#pragma unroll
  for (int j = 0; j < 4; ++j) {
    const int L = j * 512 + tid;         // 2048 chunks: 256 rows x 8
    const int r = L >> 3;
    const int c = (L & 7) ^ (r & 7);
    la[j] = L * 16;
    ga[j] = A + (size_t)(m0 + r) * 1024 + c * 8;
  }
#pragma unroll
  for (int j = 0; j < 2; ++j) {
    const int L = j * 512 + tid;         // 1024 chunks: 128 rows x 8
    const int r = L >> 3;
    const int c = (L & 7) ^ (r & 7);
    lb[j] = L * 16;
    gb[j] = B + (size_t)(n0 + r) * 1024 + c * 8;
  }
  char* const sA0 = smem;                // 3 x 32768
  char* const sB0 = smem + 98304;        // 3 x 16384

  // prologue: stage tiles 0 and 1
  {
    char* dA = sA0; char* dB = sB0;
#pragma unroll
    for (int j = 0; j < 4; ++j) { gload16(ga[j], dA + la[j]); ga[j] += 64; }
#pragma unroll
    for (int j = 0; j < 2; ++j) { gload16(gb[j], dB + lb[j]); gb[j] += 64; }
  }
  {
    char* dA = sA0 + 32768; char* dB = sB0 + 16384;
#pragma unroll
    for (int j = 0; j < 4; ++j) { gload16(ga[j], dA + la[j]); ga[j] += 64; }
#pragma unroll
    for (int j = 0; j < 2; ++j) { gload16(gb[j], dB + lb[j]); gb[j] += 64; }
  }
  asm volatile("s_waitcnt vmcnt(6)" ::: "memory");   // tile0 done, tile1 in flight
  __builtin_amdgcn_s_barrier();
  asm volatile("" ::: "memory");

  int cur = 0;
#pragma unroll 1
  for (int t = 0; t < 14; ++t) {                     // K=1024 -> 16 tiles
    int nxt = cur + 2; if (nxt >= 3) nxt -= 3;       // stage tile t+2
    QTILE(cur, nxt, true, 6);
    cur = (cur + 1 == 3) ? 0 : cur + 1;
  }
  QTILE(cur, 0, false, 0);                           // t=14: drain tile15 loads
  cur = (cur + 1 == 3) ? 0 : cur + 1;
  QTILE(cur, 0, false, 0);                           // t=15
}

#define ACC_ZERO4(acc) { _Pragma("unroll") for (int i=0;i<4;++i) \
  _Pragma("unroll") for (int j=0;j<4;++j) \
  _Pragma("unroll") for (int r=0;r<4;++r) acc[i][j][r]=0.f; }
#define ACC_ZERO2(acc) { _Pragma("unroll") for (int i=0;i<2;++i) \
  _Pragma("unroll") for (int j=0;j<4;++j) \
  _Pragma("unroll") for (int r=0;r<4;++r) acc[i][j][r]=0.f; }

// ---------- epilogue: 256x128 acc(+bias) -> bf16 C via LDS repack ----------
__device__ __forceinline__ void store256x128_bf16(
    f32x4 acc[4][4], const float* bias, int n0,
    u16* C, int m0, char* smem)
{
  const int tid = threadIdx.x, lane = tid & 63, wave = tid >> 6;
  const int quad = lane >> 4, l16 = lane & 15;
  const int wr = (wave >> 1) << 6, wc = (wave & 1) << 6;
  u16* t = (u16*)smem;                       // 256 x 136 u16
#pragma unroll
  for (int j = 0; j < 4; ++j) {
    const int nn = wc + j * 16 + l16;
    const float bj = bias[n0 + nn];
#pragma unroll
    for (int i = 0; i < 4; ++i) {
      const int mm = wr + i * 16 + quad * 4;
#pragma unroll
      for (int r = 0; r < 4; ++r)
        t[(mm + r) * 136 + nn] = f2bf(acc[i][j][r] + bj);
    }
  }
  __syncthreads();
#pragma unroll
  for (int it = 0; it < 8; ++it) {
    const int L = it * 512 + tid;              // 4096 chunks of 8 u16
    const int mm = L >> 4, cc = L & 15;
    *(uint4*)(C + (size_t)(m0 + mm) * 1024 + n0 + cc * 8) =
        *(const uint4*)(t + mm * 136 + cc * 8);
  }
}

// ---------- GEMM core 64x128: per-wave 32x64, acc[2][4] (unchanged) ----------
__device__ __forceinline__ void gemm_tile_64(
    const u16* __restrict__ A, int lda,
    const u16* __restrict__ B, int ldb,
    int m0, int n0, int kend,
    char* sA, char* sB, f32x4 acc[2][4])
{
  const int tid  = threadIdx.x;
  const int lane = tid & 63;
  const int wave = tid >> 6;
  const int quad = lane >> 4;
  const int l16  = lane & 15;
  const int wr   = (wave >> 1) << 5;   // wave row origin (0/32)
  const int wc   = (wave & 1) << 6;    // wave col origin (0/64)

  const u16* ga[2]; int la[2];
  const u16* gb[4]; int lb[4];
#pragma unroll
  for (int j = 0; j < 2; ++j) {
    const int Lb = j * 256 + wave * 64;      // 512 chunks for 64 rows
    const int L  = Lb + lane;
    const int r  = L >> 3;
    const int c  = (L & 7) ^ (r & 7);
    la[j] = Lb * 16;
    ga[j] = A + (size_t)(m0 + r) * lda + c * 8;
  }
#pragma unroll
  for (int j = 0; j < 4; ++j) {
    const int Lb = j * 256 + wave * 64;
    const int L  = Lb + lane;
    const int r  = L >> 3;
    const int c  = (L & 7) ^ (r & 7);
    lb[j] = Lb * 16;
    gb[j] = B + (size_t)(n0 + r) * ldb + c * 8;
  }

  for (int kt = 0; kt < kend; kt += 64) {
#pragma unroll
    for (int j = 0; j < 2; ++j) { gload16(ga[j], sA + la[j]); ga[j] += 64; }
#pragma unroll
    for (int j = 0; j < 4; ++j) { gload16(gb[j], sB + lb[j]); gb[j] += 64; }
    __syncthreads();
#pragma unroll
    for (int kk = 0; kk < 2; ++kk) {
      short8 af[2], bfr[4];
#pragma unroll
      for (int i = 0; i < 2; ++i) {
        const int rm = wr + i * 16 + l16;
        af[i] = *(const short8*)(sA + rm * 128 + (((kk << 2) + quad) ^ (rm & 7)) * 16);
      }
#pragma unroll
      for (int j = 0; j < 4; ++j) {
        const int rn = wc + j * 16 + l16;
        bfr[j] = *(const short8*)(sB + rn * 128 + (((kk << 2) + quad) ^ (rn & 7)) * 16);
      }
#pragma unroll
      for (int i = 0; i < 2; ++i)
#pragma unroll
        for (int j = 0; j < 4; ++j)
          acc[i][j] = __builtin_amdgcn_mfma_f32_16x16x32_bf16(af[i], bfr[j], acc[i][j], 0, 0, 0);
    }
    __syncthreads();
  }
}

// ---------- kernel 1: cast fp32 -> bf16 (x + 4 weights) + zero rowsum ----------
__global__ __launch_bounds__(256) void cast_inputs(
    const float* __restrict__ x,  const float* __restrict__ wq,
    const float* __restrict__ wk, const float* __restrict__ wv,
    const float* __restrict__ wo,
    u16* xb, u16* wqb, u16* wkb, u16* wvb, u16* wob, float* rsum)
{
  int b = blockIdx.x;
  if (b < 8) {                               // fold rowsum zeroing (8192 floats)
    float4 z = {0.f, 0.f, 0.f, 0.f};
    *(float4*)(rsum + (b * 256 + threadIdx.x) * 4) = z;
  }
  const float* src; u16* dst; int base;
  if (b < 4096) { src = x; dst = xb; base = b * 2048; }
  else {
    int r = (b - 4096) >> 9, bb = (b - 4096) & 511;
    base = bb * 2048;
    src = (r == 0) ? wq : (r == 1) ? wk : (r == 2) ? wv : wo;
    dst = (r == 0) ? wqb : (r == 1) ? wkb : (r == 2) ? wvb : wob;
  }
  int i0 = base + threadIdx.x * 8;
  float4 f0 = *(const float4*)(src + i0);
  float4 f1 = *(const float4*)(src + i0 + 4);
  short8 o;
  o[0]=(short)f2bf(f0.x); o[1]=(short)f2bf(f0.y); o[2]=(short)f2bf(f0.z); o[3]=(short)f2bf(f0.w);
  o[4]=(short)f2bf(f1.x); o[5]=(short)f2bf(f1.y); o[6]=(short)f2bf(f1.z); o[7]=(short)f2bf(f1.w);
  *(short8*)(dst + i0) = o;
}

// ---------- kernel 2: fused QKV projection, 256x128 8-phase core ----------
// grid (256, 3): x = XCD-chunked tile id (each XCD owns 4 contiguous m-tiles),
// y = which weight (q/k/v). 512 threads, 144 KiB LDS, 1 block/CU, 3 clean rounds.
__global__ __launch_bounds__(512, 2) void proj_qkv(
    const u16* __restrict__ xb,
    const u16* __restrict__ wqb, const u16* __restrict__ wkb, const u16* __restrict__ wvb,
    const float* __restrict__ bq, const float* __restrict__ bk, const float* __restrict__ bv,
    u16* q, u16* k, u16* vt)
{
  __shared__ char smem[147456];
  const int z = blockIdx.y;
  const u16* W = (z == 0) ? wqb : (z == 1) ? wkb : wvb;
  const float* bias = (z == 0) ? bq : (z == 1) ? bk : bv;
  const int id = blockIdx.x;                 // 0..255
  const int m0 = ((id & 7) * 4 + ((id >> 3) & 3)) * 256;   // XCD owns 4 m-tiles
  const int n0 = (id >> 5) * 128;

  f32x4 acc[4][4]; ACC_ZERO4(acc);
  gemm_256x128(xb, W, m0, n0, smem, acc);

  if (z < 2) {
    store256x128_bf16(acc, bias, n0, (z == 0) ? q : k, m0, smem);
  } else {
    const int tid = threadIdx.x, lane = tid & 63, wave = tid >> 6;
    const int quad = lane >> 4, l16 = lane & 15;
    const int wr = (wave >> 1) << 6, wc = (wave & 1) << 6;
    u16* t = (u16*)smem;                     // transposed: t[n_local][m_local], 128 x 264
#pragma unroll
    for (int j = 0; j < 4; ++j) {
      const int nn = wc + j * 16 + l16;
      const float bj = bias[n0 + nn];
#pragma unroll
      for (int i = 0; i < 4; ++i) {
        const int mm = wr + i * 16 + quad * 4;
#pragma unroll
        for (int r = 0; r < 4; ++r)
          t[nn * 264 + mm + r] = f2bf(acc[i][j][r] + bj);
      }
    }
    __syncthreads();
    const int b = m0 >> 10, t0 = m0 & 1023;
#pragma unroll
    for (int it = 0; it < 8; ++it) {
      const int L = it * 512 + tid;          // 128 rows x 32 chunks of 8
      const int nn = L >> 5, cc = L & 31;
      *(uint4*)(vt + ((size_t)b << 20) + (size_t)(n0 + nn) * 1024 + t0 + cc * 8) =
          *(const uint4*)(t + nn * 264 + cc * 8);
    }
  }
}

// ---------- kernel 3: P' = exp(scale*QK^T) bf16 + row sums; 64x128 tiles ----------
// grid = 8 batches x 72 lower-triangle tiles (q-tile=64 rows, k-tile=128 cols)
__global__ __launch_bounds__(256) void qk_expscores(
    const u16* __restrict__ q, const u16* __restrict__ k,
    u16* __restrict__ probs, float* __restrict__ rowsum)
{
  const int id = blockIdx.x;
  const int b = id / 72, t = id - b * 72;
  // counts per q-tile qi: (qi>>1)+1; cumulative before qi=2p is p(p+1)
  int p = (int)((__builtin_sqrtf((float)(4 * t + 1)) - 1.f) * 0.5f);
  while ((p + 1) * (p + 2) <= t) ++p;
  while (p * (p + 1) > t) --p;
  int r0 = t - p * (p + 1);
  const int qi = 2 * p + (r0 >= p + 1);
  const int kb = (r0 >= p + 1) ? r0 - (p + 1) : r0;

  __shared__ char smem[24576];
  char* sA = smem; char* sB = smem + 8192;
  const u16* A = q + ((size_t)b << 20);
  const u16* B = k + ((size_t)b << 20);
  const int m0 = qi * 64, n0 = kb * 128;

  f32x4 acc[2][4]; ACC_ZERO2(acc);
  gemm_tile_64(A, 1024, B, 1024, m0, n0, 1024, sA, sB, acc);

  const int tid = threadIdx.x, lane = tid & 63, wave = tid >> 6;
  const int quad = lane >> 4, l16 = lane & 15;
  const int wr = (wave >> 1) << 5, wc = (wave & 1) << 6;
  const bool diag = (kb == (qi >> 1));

  float part[2][4];
#pragma unroll
  for (int i = 0; i < 2; ++i)
#pragma unroll
    for (int r = 0; r < 4; ++r) part[i][r] = 0.f;

  u16* tl = (u16*)smem;                      // 64 x 136 u16 repack
#pragma unroll
  for (int j = 0; j < 4; ++j) {
    const int nn = wc + j * 16 + l16;
#pragma unroll
    for (int i = 0; i < 2; ++i) {
      const int mm = wr + i * 16 + quad * 4;
#pragma unroll
      for (int r = 0; r < 4; ++r) {
        float e = __expf(acc[i][j][r] * 0.03125f);
        if (diag && (n0 + nn) > (m0 + mm + r)) e = 0.f;  // causal mask
        part[i][r] += e;
        tl[(mm + r) * 136 + nn] = f2bf(e);
      }
    }
  }
  float* rs = rowsum + b * 1024 + m0;
#pragma unroll
  for (int i = 0; i < 2; ++i)
#pragma unroll
    for (int r = 0; r < 4; ++r) {
      float v = part[i][r];
      v += __shfl_xor(v, 1); v += __shfl_xor(v, 2);
      v += __shfl_xor(v, 4); v += __shfl_xor(v, 8);
      if (l16 == 0) atomicAdd(rs + wr + i * 16 + quad * 4 + r, v);
    }
  __syncthreads();
  u16* C = probs + ((size_t)b << 20);
#pragma unroll
  for (int it = 0; it < 4; ++it) {
    const int L = it * 256 + tid;            // 1024 chunks of 8 u16
    const int mm = L >> 4, cc = L & 15;
    *(uint4*)(C + (size_t)(m0 + mm) * 1024 + n0 + cc * 8) =
        *(const uint4*)(tl + mm * 136 + cc * 8);
  }
}

// ---------- kernel 4: O = diag(1/l) P' V; 64x128 tiles, biggest-K first ----------
__global__ __launch_bounds__(256) void pv_gemm(
    const u16* __restrict__ probs, const u16* __restrict__ vt,
    const float* __restrict__ rowsum, u16* __restrict__ o)
{
  const int id = blockIdx.x;                 // 1024 blocks
  const int b = id & 7, nb = (id >> 3) & 7, qi = 15 - (id >> 6);
  __shared__ char smem[24576];
  char* sA = smem; char* sB = smem + 8192;
  const u16* A = probs + ((size_t)b << 20);
  const u16* B = vt + ((size_t)b << 20);
  const int m0 = qi * 64, n0 = nb * 128;
  const int kend = (qi + 1) * 64;            // P' is 0/unwritten beyond this

  f32x4 acc[2][4]; ACC_ZERO2(acc);
  gemm_tile_64(A, 1024, B, 1024, m0, n0, kend, sA, sB, acc);

  const int tid = threadIdx.x, lane = tid & 63, wave = tid >> 6;
  const int quad = lane >> 4, l16 = lane & 15;
  const int wr = (wave >> 1) << 5, wc = (wave & 1) << 6;
  const float* rs = rowsum + b * 1024 + m0;
  u16* tl = (u16*)smem;                      // 64 x 136 u16
#pragma unroll
  for (int i = 0; i < 2; ++i)
#pragma unroll
    for (int r = 0; r < 4; ++r) {
      const int mm = wr + i * 16 + quad * 4 + r;
      const float inv = 1.0f / rs[mm];
#pragma unroll
      for (int j = 0; j < 4; ++j)
        tl[mm * 136 + wc + j * 16 + l16] = f2bf(acc[i][j][r] * inv);
    }
  __syncthreads();
  u16* C = o + ((size_t)b << 20);
#pragma unroll
  for (int it = 0; it < 4; ++it) {
    const int L = it * 256 + tid;
    const int mm = L >> 4, cc = L & 15;
    *(uint4*)(C + (size_t)(m0 + mm) * 1024 + n0 + cc * 8) =
        *(const uint4*)(tl + mm * 136 + cc * 8);
  }
}

// ---------- kernel 5: out = O Wo^T + bo; 256x128 8-phase core, fp32 epilogue ----------
__global__ __launch_bounds__(512, 2) void proj_o(
    const u16* __restrict__ ob, const u16* __restrict__ wob,
    const float* __restrict__ bo, float* __restrict__ out)
{
  __shared__ char smem[147456];
  const int id = blockIdx.x;                 // 0..255
  const int m0 = ((id & 7) * 4 + ((id >> 3) & 3)) * 256;
  const int n0 = (id >> 5) * 128;
  f32x4 acc[4][4]; ACC_ZERO4(acc);
  gemm_256x128(ob, wob, m0, n0, smem, acc);

  const int tid = threadIdx.x, lane = tid & 63, wave = tid >> 6;
  const int quad = lane >> 4, l16 = lane & 15;
  const int wr = (wave >> 1) << 6, wc = (wave & 1) << 6;
  float* tf = (float*)smem;                  // 256 x 132 fp32
#pragma unroll
  for (int j = 0; j < 4; ++j) {
    const int nn = wc + j * 16 + l16;
    const float bj = bo[n0 + nn];
#pragma unroll
    for (int i = 0; i < 4; ++i)
#pragma unroll
      for (int r = 0; r < 4; ++r)
        tf[(wr + i * 16 + quad * 4 + r) * 132 + nn] = acc[i][j][r] + bj;
  }
  __syncthreads();
#pragma unroll
  for (int it = 0; it < 16; ++it) {
    const int L = it * 512 + tid;            // 256 rows x 32 float4
    const int mm = L >> 5, cc = L & 31;
    *(float4*)(out + (size_t)(m0 + mm) * 1024 + n0 + cc * 4) =
        *(const float4*)(tf + mm * 132 + cc * 4);
  }
}

// ---------- launch ----------
extern "C" void kernel_launch(void* const* d_in, const int* in_sizes, int n_in,
                              void* d_out, int out_size, void* d_ws, size_t ws_size,
                              hipStream_t stream) {
  const float* x  = (const float*)d_in[0];
  const float* wq = (const float*)d_in[1];
  const float* bq = (const float*)d_in[2];
  const float* wk = (const float*)d_in[3];
  const float* bk = (const float*)d_in[4];
  const float* wv = (const float*)d_in[5];
  const float* bv = (const float*)d_in[6];
  const float* wo = (const float*)d_in[7];
  const float* bo = (const float*)d_in[8];
  float* out = (float*)d_out;

  char* ws = (char*)d_ws;
  const size_t MB = 1u << 20;
  u16*  xb  = (u16*)(ws);            // 16 MB (x bf16; reused later as O bf16)
  u16*  wqb = (u16*)(ws + 16*MB);
  u16*  wkb = (u16*)(ws + 18*MB);
  u16*  wvb = (u16*)(ws + 20*MB);
  u16*  wob = (u16*)(ws + 22*MB);
  u16*  qb  = (u16*)(ws + 24*MB);
  u16*  kb  = (u16*)(ws + 40*MB);
  u16*  vtb = (u16*)(ws + 56*MB);    // V transposed per batch
  u16*  pr  = (u16*)(ws + 72*MB);    // bf16 unnormalized probs P'
  float* rsum = (float*)(ws + 88*MB);// 32 KB row sums

  cast_inputs<<<6144, 256, 0, stream>>>(x, wq, wk, wv, wo, xb, wqb, wkb, wvb, wob, rsum);
  proj_qkv<<<dim3(256, 3), 512, 0, stream>>>(xb, wqb, wkb, wvb, bq, bk, bv, qb, kb, vtb);
  qk_expscores<<<576, 256, 0, stream>>>(qb, kb, pr, rsum);
  pv_gemm<<<1024, 256, 0, stream>>>(pr, vtb, rsum, xb /* O reuses x region */);
  proj_o<<<256, 512, 0, stream>>>(xb, wob, bo, out);
}

// Round 2
// 225.858 us; speedup vs baseline: 1.0367x; 1.0367x over previous
//
#include <hip/hip_runtime.h>

typedef unsigned short u16;
typedef __attribute__((ext_vector_type(8))) short short8;
typedef __attribute__((ext_vector_type(4))) float f32x4;

// ---------- helpers ----------

__device__ __forceinline__ u16 f2bf(float f) {
  unsigned u = __builtin_bit_cast(unsigned, f);
  u += 0x7fffu + ((u >> 16) & 1u);   // RNE
  return (u16)(u >> 16);
}

__device__ __forceinline__ void gload16(const void* g, void* l) {
  __builtin_amdgcn_global_load_lds(
      (const __attribute__((address_space(1))) unsigned*)g,
      (__attribute__((address_space(3))) unsigned*)l, 16, 0, 0);
}

// ================================================================
// 256x128 software-pipelined GEMM core (K=1024), 512 threads / 8 waves.
// Waves 4(M)x2(N), each owns 64x64 -> acc[4][4].
// LDS: 3 K-tile buffers of (A 256x64 + B 128x64) bf16 = 48 KB each,
// 16B-chunk XOR swizzle. Prefetch distance 2 tiles, vmcnt(6) in loop.
// ONE barrier per K-tile. ds_reads for the NEXT phase issue BEFORE the
// current phase's MFMA cluster and complete under it (counted lgkmcnt):
//   phase0: G(3) ; read A1(4) ; lgkm(4) ; 16 MFMA (A0,B)
//   phase1: G(3) ; vm(6)+lgkm(0) ; BAR ; read B',A0'(12) ; 16 MFMA (A1,B)
// Race-freedom: all reads of buf[t-1] are counter-drained before the
// t-1 -> t barrier; buf[t-1] is only rewritten (as buf[t+2]) after it.
// ================================================================

#define PTILE(RB_C, RB_N, DOSTAGE, VM, LAST)                                  \
  {                                                                           \
    char* cA = sA0 + cur * 49152;                                             \
    /* ---- phase 0 ---- */                                                   \
    if (DOSTAGE) {                                                            \
      const int ns = (cur + 2 >= 3) ? cur - 1 : cur + 2;                      \
      char* dA = sA0 + ns * 49152;                                            \
      _Pragma("unroll") for (int j = 0; j < 3; ++j) {                         \
        gload16(ga[j], dA + la[j]); ga[j] += 64; }                            \
    }                                                                         \
    _Pragma("unroll") for (int kk = 0; kk < 2; ++kk)                          \
      _Pragma("unroll") for (int i = 0; i < 2; ++i) {                         \
        const int rm = wr + 32 + i * 16 + l16;                                \
        a1f[kk][i] = *(const short8*)(cA + rm * 128 +                         \
            (((kk << 2) + quad) ^ (rm & 7)) * 16);                            \
      }                                                                       \
    asm volatile("s_waitcnt lgkmcnt(4)" ::: "memory");                        \
    __builtin_amdgcn_sched_barrier(0);                                        \
    __builtin_amdgcn_s_setprio(1);                                            \
    _Pragma("unroll") for (int kk = 0; kk < 2; ++kk)                          \
      _Pragma("unroll") for (int i = 0; i < 2; ++i)                           \
        _Pragma("unroll") for (int j = 0; j < 4; ++j)                         \
          acc[i][j] = __builtin_amdgcn_mfma_f32_16x16x32_bf16(                \
              a0f[kk][i], RB_C[kk][j], acc[i][j], 0, 0, 0);                   \
    __builtin_amdgcn_s_setprio(0);                                            \
    /* ---- phase 1 ---- */                                                   \
    if (DOSTAGE) {                                                            \
      const int ns = (cur + 2 >= 3) ? cur - 1 : cur + 2;                      \
      char* dA = sA0 + ns * 49152; char* dB = dA + 32768;                     \
      gload16(ga[3], dA + la[3]); ga[3] += 64;                                \
      _Pragma("unroll") for (int j = 0; j < 2; ++j) {                         \
        gload16(gb[j], dB + lb[j]); gb[j] += 64; }                            \
    }                                                                         \
    if (!(LAST)) {                                                            \
      asm volatile("s_waitcnt vmcnt(" #VM ") lgkmcnt(0)" ::: "memory");       \
      __builtin_amdgcn_s_barrier();                                           \
      asm volatile("" ::: "memory");                                          \
      const int nc = (cur + 1 >= 3) ? 0 : cur + 1;                            \
      char* nA = sA0 + nc * 49152; char* nB = nA + 32768;                     \
      _Pragma("unroll") for (int kk = 0; kk < 2; ++kk)                        \
        _Pragma("unroll") for (int j = 0; j < 4; ++j) {                       \
          const int rn = wc + j * 16 + l16;                                   \
          RB_N[kk][j] = *(const short8*)(nB + rn * 128 +                      \
              (((kk << 2) + quad) ^ (rn & 7)) * 16);                          \
        }                                                                     \
      _Pragma("unroll") for (int kk = 0; kk < 2; ++kk)                        \
        _Pragma("unroll") for (int i = 0; i < 2; ++i) {                       \
          const int rm = wr + i * 16 + l16;                                   \
          a0f[kk][i] = *(const short8*)(nA + rm * 128 +                       \
              (((kk << 2) + quad) ^ (rm & 7)) * 16);                          \
        }                                                                     \
    } else {                                                                  \
      asm volatile("s_waitcnt lgkmcnt(0)" ::: "memory");                      \
    }                                                                         \
    __builtin_amdgcn_sched_barrier(0);                                        \
    __builtin_amdgcn_s_setprio(1);                                            \
    _Pragma("unroll") for (int kk = 0; kk < 2; ++kk)                          \
      _Pragma("unroll") for (int i = 0; i < 2; ++i)                           \
        _Pragma("unroll") for (int j = 0; j < 4; ++j)                         \
          acc[2 + i][j] = __builtin_amdgcn_mfma_f32_16x16x32_bf16(            \
              a1f[kk][i], RB_C[kk][j], acc[2 + i][j], 0, 0, 0);               \
    __builtin_amdgcn_s_setprio(0);                                            \
    cur = (cur + 1 >= 3) ? 0 : cur + 1;                                       \
  }

__device__ __forceinline__ void gemm_256x128(
    const u16* __restrict__ A, const u16* __restrict__ B,
    int m0, int n0, char* smem, f32x4 acc[4][4])
{
  const int tid  = threadIdx.x;          // 0..511
  const int lane = tid & 63;
  const int quad = lane >> 4;
  const int l16  = lane & 15;
  const int wave = tid >> 6;             // 0..7
  const int wr   = (wave >> 1) << 6;     // 0,64,128,192
  const int wc   = (wave & 1) << 6;      // 0,64

  // staging sources (pre-swizzled global addr, linear LDS dest)
  const u16* ga[4]; int la[4];
  const u16* gb[2]; int lb[2];
#pragma unroll
  for (int j = 0; j < 4; ++j) {
    const int L = j * 512 + tid;         // 2048 chunks: 256 rows x 8
    const int r = L >> 3;
    const int c = (L & 7) ^ (r & 7);
    la[j] = L * 16;
    ga[j] = A + (size_t)(m0 + r) * 1024 + c * 8;
  }
#pragma unroll
  for (int j = 0; j < 2; ++j) {
    const int L = j * 512 + tid;         // 1024 chunks: 128 rows x 8
    const int r = L >> 3;
    const int c = (L & 7) ^ (r & 7);
    lb[j] = L * 16;
    gb[j] = B + (size_t)(n0 + r) * 1024 + c * 8;
  }
  char* const sA0 = smem;                // buf b: A at b*49152, B at +32768

  // register fragment sets
  short8 bfr0[2][4], bfr1[2][4];         // B frags, double-buffered
  short8 a0f[2][2], a1f[2][2];           // A frags rows 0..31 / 32..63

  // prologue: stage tiles 0 and 1 (6 gloads each)
  {
    char* dA = sA0; char* dB = sA0 + 32768;
#pragma unroll
    for (int j = 0; j < 4; ++j) { gload16(ga[j], dA + la[j]); ga[j] += 64; }
#pragma unroll
    for (int j = 0; j < 2; ++j) { gload16(gb[j], dB + lb[j]); gb[j] += 64; }
    dA = sA0 + 49152; dB = dA + 32768;
#pragma unroll
    for (int j = 0; j < 4; ++j) { gload16(ga[j], dA + la[j]); ga[j] += 64; }
#pragma unroll
    for (int j = 0; j < 2; ++j) { gload16(gb[j], dB + lb[j]); gb[j] += 64; }
  }
  asm volatile("s_waitcnt vmcnt(6)" ::: "memory");   // tile0 done, tile1 in flight
  __builtin_amdgcn_s_barrier();
  asm volatile("" ::: "memory");
  // pre-read tile0's B + A0 frags (matches steady-state R')
  {
    char* nA = sA0; char* nB = sA0 + 32768;
#pragma unroll
    for (int kk = 0; kk < 2; ++kk)
#pragma unroll
      for (int j = 0; j < 4; ++j) {
        const int rn = wc + j * 16 + l16;
        bfr0[kk][j] = *(const short8*)(nB + rn * 128 + (((kk << 2) + quad) ^ (rn & 7)) * 16);
      }
#pragma unroll
    for (int kk = 0; kk < 2; ++kk)
#pragma unroll
      for (int i = 0; i < 2; ++i) {
        const int rm = wr + i * 16 + l16;
        a0f[kk][i] = *(const short8*)(nA + rm * 128 + (((kk << 2) + quad) ^ (rm & 7)) * 16);
      }
  }

  int cur = 0;
#pragma unroll 1
  for (int it = 0; it < 7; ++it) {       // tiles 0..13 (stage tiles 2..15)
    PTILE(bfr0, bfr1, true, 6, false);
    PTILE(bfr1, bfr0, true, 6, false);
  }
  PTILE(bfr0, bfr1, false, 0, false);    // tile 14: drain tile15's loads
  PTILE(bfr1, bfr0, false, 0, true);     // tile 15: last
  __syncthreads();                       // epilogue may rewrite LDS
}

#define ACC_ZERO4(acc) { _Pragma("unroll") for (int i=0;i<4;++i) \
  _Pragma("unroll") for (int j=0;j<4;++j) \
  _Pragma("unroll") for (int r=0;r<4;++r) acc[i][j][r]=0.f; }
#define ACC_ZERO2(acc) { _Pragma("unroll") for (int i=0;i<2;++i) \
  _Pragma("unroll") for (int j=0;j<4;++j) \
  _Pragma("unroll") for (int r=0;r<4;++r) acc[i][j][r]=0.f; }

// ---------- epilogue: 256x128 acc(+bias) -> bf16 C via LDS repack ----------
__device__ __forceinline__ void store256x128_bf16(
    f32x4 acc[4][4], const float* bias, int n0,
    u16* C, int m0, char* smem)
{
  const int tid = threadIdx.x, lane = tid & 63, wave = tid >> 6;
  const int quad = lane >> 4, l16 = lane & 15;
  const int wr = (wave >> 1) << 6, wc = (wave & 1) << 6;
  u16* t = (u16*)smem;                       // 256 x 136 u16
#pragma unroll
  for (int j = 0; j < 4; ++j) {
    const int nn = wc + j * 16 + l16;
    const float bj = bias[n0 + nn];
#pragma unroll
    for (int i = 0; i < 4; ++i) {
      const int mm = wr + i * 16 + quad * 4;
#pragma unroll
      for (int r = 0; r < 4; ++r)
        t[(mm + r) * 136 + nn] = f2bf(acc[i][j][r] + bj);
    }
  }
  __syncthreads();
#pragma unroll
  for (int it = 0; it < 8; ++it) {
    const int L = it * 512 + tid;              // 4096 chunks of 8 u16
    const int mm = L >> 4, cc = L & 15;
    *(uint4*)(C + (size_t)(m0 + mm) * 1024 + n0 + cc * 8) =
        *(const uint4*)(t + mm * 136 + cc * 8);
  }
}

// ---------- GEMM core 64x128: per-wave 32x64, acc[2][4] (unchanged) ----------
__device__ __forceinline__ void gemm_tile_64(
    const u16* __restrict__ A, int lda,
    const u16* __restrict__ B, int ldb,
    int m0, int n0, int kend,
    char* sA, char* sB, f32x4 acc[2][4])
{
  const int tid  = threadIdx.x;
  const int lane = tid & 63;
  const int wave = tid >> 6;
  const int quad = lane >> 4;
  const int l16  = lane & 15;
  const int wr   = (wave >> 1) << 5;   // wave row origin (0/32)
  const int wc   = (wave & 1) << 6;    // wave col origin (0/64)

  const u16* ga[2]; int la[2];
  const u16* gb[4]; int lb[4];
#pragma unroll
  for (int j = 0; j < 2; ++j) {
    const int Lb = j * 256 + wave * 64;      // 512 chunks for 64 rows
    const int L  = Lb + lane;
    const int r  = L >> 3;
    const int c  = (L & 7) ^ (r & 7);
    la[j] = Lb * 16;
    ga[j] = A + (size_t)(m0 + r) * lda + c * 8;
  }
#pragma unroll
  for (int j = 0; j < 4; ++j) {
    const int Lb = j * 256 + wave * 64;
    const int L  = Lb + lane;
    const int r  = L >> 3;
    const int c  = (L & 7) ^ (r & 7);
    lb[j] = Lb * 16;
    gb[j] = B + (size_t)(n0 + r) * ldb + c * 8;
  }

  for (int kt = 0; kt < kend; kt += 64) {
#pragma unroll
    for (int j = 0; j < 2; ++j) { gload16(ga[j], sA + la[j]); ga[j] += 64; }
#pragma unroll
    for (int j = 0; j < 4; ++j) { gload16(gb[j], sB + lb[j]); gb[j] += 64; }
    __syncthreads();
#pragma unroll
    for (int kk = 0; kk < 2; ++kk) {
      short8 af[2], bfr[4];
#pragma unroll
      for (int i = 0; i < 2; ++i) {
        const int rm = wr + i * 16 + l16;
        af[i] = *(const short8*)(sA + rm * 128 + (((kk << 2) + quad) ^ (rm & 7)) * 16);
      }
#pragma unroll
      for (int j = 0; j < 4; ++j) {
        const int rn = wc + j * 16 + l16;
        bfr[j] = *(const short8*)(sB + rn * 128 + (((kk << 2) + quad) ^ (rn & 7)) * 16);
      }
#pragma unroll
      for (int i = 0; i < 2; ++i)
#pragma unroll
        for (int j = 0; j < 4; ++j)
          acc[i][j] = __builtin_amdgcn_mfma_f32_16x16x32_bf16(af[i], bfr[j], acc[i][j], 0, 0, 0);
    }
    __syncthreads();
  }
}

// ---------- kernel 1: cast fp32 -> bf16 (x + 4 weights) + zero rowsum ----------
__global__ __launch_bounds__(256) void cast_inputs(
    const float* __restrict__ x,  const float* __restrict__ wq,
    const float* __restrict__ wk, const float* __restrict__ wv,
    const float* __restrict__ wo,
    u16* xb, u16* wqb, u16* wkb, u16* wvb, u16* wob, float* rsum)
{
  int b = blockIdx.x;
  if (b < 8) {                               // fold rowsum zeroing (8192 floats)
    float4 z = {0.f, 0.f, 0.f, 0.f};
    *(float4*)(rsum + (b * 256 + threadIdx.x) * 4) = z;
  }
  const float* src; u16* dst; int base;
  if (b < 4096) { src = x; dst = xb; base = b * 2048; }
  else {
    int r = (b - 4096) >> 9, bb = (b - 4096) & 511;
    base = bb * 2048;
    src = (r == 0) ? wq : (r == 1) ? wk : (r == 2) ? wv : wo;
    dst = (r == 0) ? wqb : (r == 1) ? wkb : (r == 2) ? wvb : wob;
  }
  int i0 = base + threadIdx.x * 8;
  float4 f0 = *(const float4*)(src + i0);
  float4 f1 = *(const float4*)(src + i0 + 4);
  short8 o;
  o[0]=(short)f2bf(f0.x); o[1]=(short)f2bf(f0.y); o[2]=(short)f2bf(f0.z); o[3]=(short)f2bf(f0.w);
  o[4]=(short)f2bf(f1.x); o[5]=(short)f2bf(f1.y); o[6]=(short)f2bf(f1.z); o[7]=(short)f2bf(f1.w);
  *(short8*)(dst + i0) = o;
}

// ---------- kernel 2: fused QKV projection, pipelined 256x128 core ----------
// grid (256, 3): x = XCD-chunked tile id (each XCD owns 4 contiguous m-tiles),
// y = which weight (q/k/v). 512 threads, 144 KiB LDS, 1 block/CU, 3 clean rounds.
__global__ __launch_bounds__(512, 2) void proj_qkv(
    const u16* __restrict__ xb,
    const u16* __restrict__ wqb, const u16* __restrict__ wkb, const u16* __restrict__ wvb,
    const float* __restrict__ bq, const float* __restrict__ bk, const float* __restrict__ bv,
    u16* q, u16* k, u16* vt)
{
  __shared__ char smem[147456];
  const int z = blockIdx.y;
  const u16* W = (z == 0) ? wqb : (z == 1) ? wkb : wvb;
  const float* bias = (z == 0) ? bq : (z == 1) ? bk : bv;
  const int id = blockIdx.x;                 // 0..255
  const int m0 = ((id & 7) * 4 + ((id >> 3) & 3)) * 256;   // XCD owns 4 m-tiles
  const int n0 = (id >> 5) * 128;

  f32x4 acc[4][4]; ACC_ZERO4(acc);
  gemm_256x128(xb, W, m0, n0, smem, acc);

  if (z < 2) {
    store256x128_bf16(acc, bias, n0, (z == 0) ? q : k, m0, smem);
  } else {
    const int tid = threadIdx.x, lane = tid & 63, wave = tid >> 6;
    const int quad = lane >> 4, l16 = lane & 15;
    const int wr = (wave >> 1) << 6, wc = (wave & 1) << 6;
    u16* t = (u16*)smem;                     // transposed: t[n_local][m_local], 128 x 264
#pragma unroll
    for (int j = 0; j < 4; ++j) {
      const int nn = wc + j * 16 + l16;
      const float bj = bias[n0 + nn];
#pragma unroll
      for (int i = 0; i < 4; ++i) {
        const int mm = wr + i * 16 + quad * 4;
#pragma unroll
        for (int r = 0; r < 4; ++r)
          t[nn * 264 + mm + r] = f2bf(acc[i][j][r] + bj);
      }
    }
    __syncthreads();
    const int b = m0 >> 10, t0 = m0 & 1023;
#pragma unroll
    for (int it = 0; it < 8; ++it) {
      const int L = it * 512 + tid;          // 128 rows x 32 chunks of 8
      const int nn = L >> 5, cc = L & 31;
      *(uint4*)(vt + ((size_t)b << 20) + (size_t)(n0 + nn) * 1024 + t0 + cc * 8) =
          *(const uint4*)(t + nn * 264 + cc * 8);
    }
  }
}

// ---------- kernel 3: P' = exp(scale*QK^T) bf16 + row sums; 64x128 tiles ----------
// grid = 8 batches x 72 lower-triangle tiles (q-tile=64 rows, k-tile=128 cols)
__global__ __launch_bounds__(256) void qk_expscores(
    const u16* __restrict__ q, const u16* __restrict__ k,
    u16* __restrict__ probs, float* __restrict__ rowsum)
{
  const int id = blockIdx.x;
  const int b = id / 72, t = id - b * 72;
  // counts per q-tile qi: (qi>>1)+1; cumulative before qi=2p is p(p+1)
  int p = (int)((__builtin_sqrtf((float)(4 * t + 1)) - 1.f) * 0.5f);
  while ((p + 1) * (p + 2) <= t) ++p;
  while (p * (p + 1) > t) --p;
  int r0 = t - p * (p + 1);
  const int qi = 2 * p + (r0 >= p + 1);
  const int kb = (r0 >= p + 1) ? r0 - (p + 1) : r0;

  __shared__ char smem[24576];
  char* sA = smem; char* sB = smem + 8192;
  const u16* A = q + ((size_t)b << 20);
  const u16* B = k + ((size_t)b << 20);
  const int m0 = qi * 64, n0 = kb * 128;

  f32x4 acc[2][4]; ACC_ZERO2(acc);
  gemm_tile_64(A, 1024, B, 1024, m0, n0, 1024, sA, sB, acc);

  const int tid = threadIdx.x, lane = tid & 63, wave = tid >> 6;
  const int quad = lane >> 4, l16 = lane & 15;
  const int wr = (wave >> 1) << 5, wc = (wave & 1) << 6;
  const bool diag = (kb == (qi >> 1));

  float part[2][4];
#pragma unroll
  for (int i = 0; i < 2; ++i)
#pragma unroll
    for (int r = 0; r < 4; ++r) part[i][r] = 0.f;

  u16* tl = (u16*)smem;                      // 64 x 136 u16 repack
#pragma unroll
  for (int j = 0; j < 4; ++j) {
    const int nn = wc + j * 16 + l16;
#pragma unroll
    for (int i = 0; i < 2; ++i) {
      const int mm = wr + i * 16 + quad * 4;
#pragma unroll
      for (int r = 0; r < 4; ++r) {
        float e = __expf(acc[i][j][r] * 0.03125f);
        if (diag && (n0 + nn) > (m0 + mm + r)) e = 0.f;  // causal mask
        part[i][r] += e;
        tl[(mm + r) * 136 + nn] = f2bf(e);
      }
    }
  }
  float* rs = rowsum + b * 1024 + m0;
#pragma unroll
  for (int i = 0; i < 2; ++i)
#pragma unroll
    for (int r = 0; r < 4; ++r) {
      float v = part[i][r];
      v += __shfl_xor(v, 1); v += __shfl_xor(v, 2);
      v += __shfl_xor(v, 4); v += __shfl_xor(v, 8);
      if (l16 == 0) atomicAdd(rs + wr + i * 16 + quad * 4 + r, v);
    }
  __syncthreads();
  u16* C = probs + ((size_t)b << 20);
#pragma unroll
  for (int it = 0; it < 4; ++it) {
    const int L = it * 256 + tid;            // 1024 chunks of 8 u16
    const int mm = L >> 4, cc = L & 15;
    *(uint4*)(C + (size_t)(m0 + mm) * 1024 + n0 + cc * 8) =
        *(const uint4*)(tl + mm * 136 + cc * 8);
  }
}

// ---------- kernel 4: O = diag(1/l) P' V; 64x128 tiles, biggest-K first ----------
__global__ __launch_bounds__(256) void pv_gemm(
    const u16* __restrict__ probs, const u16* __restrict__ vt,
    const float* __restrict__ rowsum, u16* __restrict__ o)
{
  const int id = blockIdx.x;                 // 1024 blocks
  const int b = id & 7, nb = (id >> 3) & 7, qi = 15 - (id >> 6);
  __shared__ char smem[24576];
  char* sA = smem; char* sB = smem + 8192;
  const u16* A = probs + ((size_t)b << 20);
  const u16* B = vt + ((size_t)b << 20);
  const int m0 = qi * 64, n0 = nb * 128;
  const int kend = (qi + 1) * 64;            // P' is 0/unwritten beyond this

  f32x4 acc[2][4]; ACC_ZERO2(acc);
  gemm_tile_64(A, 1024, B, 1024, m0, n0, kend, sA, sB, acc);

  const int tid = threadIdx.x, lane = tid & 63, wave = tid >> 6;
  const int quad = lane >> 4, l16 = lane & 15;
  const int wr = (wave >> 1) << 5, wc = (wave & 1) << 6;
  const float* rs = rowsum + b * 1024 + m0;
  u16* tl = (u16*)smem;                      // 64 x 136 u16
#pragma unroll
  for (int i = 0; i < 2; ++i)
#pragma unroll
    for (int r = 0; r < 4; ++r) {
      const int mm = wr + i * 16 + quad * 4 + r;
      const float inv = 1.0f / rs[mm];
#pragma unroll
      for (int j = 0; j < 4; ++j)
        tl[mm * 136 + wc + j * 16 + l16] = f2bf(acc[i][j][r] * inv);
    }
  __syncthreads();
  u16* C = o + ((size_t)b << 20);
#pragma unroll
  for (int it = 0; it < 4; ++it) {
    const int L = it * 256 + tid;
    const int mm = L >> 4, cc = L & 15;
    *(uint4*)(C + (size_t)(m0 + mm) * 1024 + n0 + cc * 8) =
        *(const uint4*)(tl + mm * 136 + cc * 8);
  }
}

// ---------- kernel 5: out = O Wo^T + bo; pipelined 256x128 core, fp32 epilogue ----------
__global__ __launch_bounds__(512, 2) void proj_o(
    const u16* __restrict__ ob, const u16* __restrict__ wob,
    const float* __restrict__ bo, float* __restrict__ out)
{
  __shared__ char smem[147456];
  const int id = blockIdx.x;                 // 0..255
  const int m0 = ((id & 7) * 4 + ((id >> 3) & 3)) * 256;
  const int n0 = (id >> 5) * 128;
  f32x4 acc[4][4]; ACC_ZERO4(acc);
  gemm_256x128(ob, wob, m0, n0, smem, acc);

  const int tid = threadIdx.x, lane = tid & 63, wave = tid >> 6;
  const int quad = lane >> 4, l16 = lane & 15;
  const int wr = (wave >> 1) << 6, wc = (wave & 1) << 6;
  float* tf = (float*)smem;                  // 256 x 132 fp32
#pragma unroll
  for (int j = 0; j < 4; ++j) {
    const int nn = wc + j * 16 + l16;
    const float bj = bo[n0 + nn];
#pragma unroll
    for (int i = 0; i < 4; ++i)
#pragma unroll
      for (int r = 0; r < 4; ++r)
        tf[(wr + i * 16 + quad * 4 + r) * 132 + nn] = acc[i][j][r] + bj;
  }
  __syncthreads();
#pragma unroll
  for (int it = 0; it < 16; ++it) {
    const int L = it * 512 + tid;            // 256 rows x 32 float4
    const int mm = L >> 5, cc = L & 31;
    *(float4*)(out + (size_t)(m0 + mm) * 1024 + n0 + cc * 4) =
        *(const float4*)(tf + mm * 132 + cc * 4);
  }
}

// ---------- launch ----------
extern "C" void kernel_launch(void* const* d_in, const int* in_sizes, int n_in,
                              void* d_out, int out_size, void* d_ws, size_t ws_size,
                              hipStream_t stream) {
  const float* x  = (const float*)d_in[0];
  const float* wq = (const float*)d_in[1];
  const float* bq = (const float*)d_in[2];
  const float* wk = (const float*)d_in[3];
  const float* bk = (const float*)d_in[4];
  const float* wv = (const float*)d_in[5];
  const float* bv = (const float*)d_in[6];
  const float* wo = (const float*)d_in[7];
  const float* bo = (const float*)d_in[8];
  float* out = (float*)d_out;

  char* ws = (char*)d_ws;
  const size_t MB = 1u << 20;
  u16*  xb  = (u16*)(ws);            // 16 MB (x bf16; reused later as O bf16)
  u16*  wqb = (u16*)(ws + 16*MB);
  u16*  wkb = (u16*)(ws + 18*MB);
  u16*  wvb = (u16*)(ws + 20*MB);
  u16*  wob = (u16*)(ws + 22*MB);
  u16*  qb  = (u16*)(ws + 24*MB);
  u16*  kb  = (u16*)(ws + 40*MB);
  u16*  vtb = (u16*)(ws + 56*MB);    // V transposed per batch
  u16*  pr  = (u16*)(ws + 72*MB);    // bf16 unnormalized probs P'
  float* rsum = (float*)(ws + 88*MB);// 32 KB row sums

  cast_inputs<<<6144, 256, 0, stream>>>(x, wq, wk, wv, wo, xb, wqb, wkb, wvb, wob, rsum);
  proj_qkv<<<dim3(256, 3), 512, 0, stream>>>(xb, wqb, wkb, wvb, bq, bk, bv, qb, kb, vtb);
  qk_expscores<<<576, 256, 0, stream>>>(qb, kb, pr, rsum);
  pv_gemm<<<1024, 256, 0, stream>>>(pr, vtb, rsum, xb /* O reuses x region */);
  proj_o<<<256, 512, 0, stream>>>(xb, wob, bo, out);
}

// Round 3
// 211.910 us; speedup vs baseline: 1.1049x; 1.0658x over previous
//
#include <hip/hip_runtime.h>

typedef unsigned short u16;
typedef __attribute__((ext_vector_type(8))) short short8;
typedef __attribute__((ext_vector_type(4))) float f32x4;

// ---------- helpers ----------

__device__ __forceinline__ u16 f2bf(float f) {
  unsigned u = __builtin_bit_cast(unsigned, f);
  u += 0x7fffu + ((u >> 16) & 1u);   // RNE
  return (u16)(u >> 16);
}

__device__ __forceinline__ void gload16(const void* g, void* l) {
  __builtin_amdgcn_global_load_lds(
      (const __attribute__((address_space(1))) unsigned*)g,
      (__attribute__((address_space(3))) unsigned*)l, 16, 0, 0);
}

// ================================================================
// 256x128 software-pipelined GEMM core, 512 threads / 8 waves.
// Waves 4(M)x2(N), each owns 64x64 -> acc[4][4]. K = ntiles*64 (ntiles even,
// >=4). LDS: 3 K-tile buffers of (A 256x64 + B 128x64) bf16 = 48 KB each,
// 16B-chunk XOR swizzle. Prefetch distance 2 tiles, vmcnt(6) in loop.
// ONE barrier per K-tile; next-phase ds_reads issue before the current
// phase's MFMA cluster and complete under it (counted lgkmcnt).
// ================================================================

#define PTILE(RB_C, RB_N, DOSTAGE, VM, LAST)                                  \
  {                                                                           \
    char* cA = sA0 + cur * 49152;                                             \
    /* ---- phase 0 ---- */                                                   \
    if (DOSTAGE) {                                                            \
      const int ns = (cur + 2 >= 3) ? cur - 1 : cur + 2;                      \
      char* dA = sA0 + ns * 49152;                                            \
      _Pragma("unroll") for (int j = 0; j < 3; ++j) {                         \
        gload16(ga[j], dA + la[j]); ga[j] += 64; }                            \
    }                                                                         \
    _Pragma("unroll") for (int kk = 0; kk < 2; ++kk)                          \
      _Pragma("unroll") for (int i = 0; i < 2; ++i) {                         \
        const int rm = wr + 32 + i * 16 + l16;                                \
        a1f[kk][i] = *(const short8*)(cA + rm * 128 +                         \
            (((kk << 2) + quad) ^ (rm & 7)) * 16);                            \
      }                                                                       \
    asm volatile("s_waitcnt lgkmcnt(4)" ::: "memory");                        \
    __builtin_amdgcn_sched_barrier(0);                                        \
    __builtin_amdgcn_s_setprio(1);                                            \
    _Pragma("unroll") for (int kk = 0; kk < 2; ++kk)                          \
      _Pragma("unroll") for (int i = 0; i < 2; ++i)                           \
        _Pragma("unroll") for (int j = 0; j < 4; ++j)                         \
          acc[i][j] = __builtin_amdgcn_mfma_f32_16x16x32_bf16(                \
              a0f[kk][i], RB_C[kk][j], acc[i][j], 0, 0, 0);                   \
    __builtin_amdgcn_s_setprio(0);                                            \
    /* ---- phase 1 ---- */                                                   \
    if (DOSTAGE) {                                                            \
      const int ns = (cur + 2 >= 3) ? cur - 1 : cur + 2;                      \
      char* dA = sA0 + ns * 49152; char* dB = dA + 32768;                     \
      gload16(ga[3], dA + la[3]); ga[3] += 64;                                \
      _Pragma("unroll") for (int j = 0; j < 2; ++j) {                         \
        gload16(gb[j], dB + lb[j]); gb[j] += 64; }                            \
    }                                                                         \
    if (!(LAST)) {                                                            \
      asm volatile("s_waitcnt vmcnt(" #VM ") lgkmcnt(0)" ::: "memory");       \
      __builtin_amdgcn_s_barrier();                                           \
      asm volatile("" ::: "memory");                                          \
      const int nc = (cur + 1 >= 3) ? 0 : cur + 1;                            \
      char* nA = sA0 + nc * 49152; char* nB = nA + 32768;                     \
      _Pragma("unroll") for (int kk = 0; kk < 2; ++kk)                        \
        _Pragma("unroll") for (int j = 0; j < 4; ++j) {                       \
          const int rn = wc + j * 16 + l16;                                   \
          RB_N[kk][j] = *(const short8*)(nB + rn * 128 +                      \
              (((kk << 2) + quad) ^ (rn & 7)) * 16);                          \
        }                                                                     \
      _Pragma("unroll") for (int kk = 0; kk < 2; ++kk)                        \
        _Pragma("unroll") for (int i = 0; i < 2; ++i) {                       \
          const int rm = wr + i * 16 + l16;                                   \
          a0f[kk][i] = *(const short8*)(nA + rm * 128 +                       \
              (((kk << 2) + quad) ^ (rm & 7)) * 16);                          \
        }                                                                     \
    } else {                                                                  \
      asm volatile("s_waitcnt lgkmcnt(0)" ::: "memory");                      \
    }                                                                         \
    __builtin_amdgcn_sched_barrier(0);                                        \
    __builtin_amdgcn_s_setprio(1);                                            \
    _Pragma("unroll") for (int kk = 0; kk < 2; ++kk)                          \
      _Pragma("unroll") for (int i = 0; i < 2; ++i)                           \
        _Pragma("unroll") for (int j = 0; j < 4; ++j)                         \
          acc[2 + i][j] = __builtin_amdgcn_mfma_f32_16x16x32_bf16(            \
              a1f[kk][i], RB_C[kk][j], acc[2 + i][j], 0, 0, 0);               \
    __builtin_amdgcn_s_setprio(0);                                            \
    cur = (cur + 1 >= 3) ? 0 : cur + 1;                                       \
  }

__device__ __forceinline__ void gemm_256x128(
    const u16* __restrict__ A, const u16* __restrict__ B,
    int m0, int n0, int ntiles, char* smem, f32x4 acc[4][4])
{
  const int tid  = threadIdx.x;          // 0..511
  const int lane = tid & 63;
  const int quad = lane >> 4;
  const int l16  = lane & 15;
  const int wave = tid >> 6;             // 0..7
  const int wr   = (wave >> 1) << 6;     // 0,64,128,192
  const int wc   = (wave & 1) << 6;      // 0,64

  // staging sources (pre-swizzled global addr, linear LDS dest)
  const u16* ga[4]; int la[4];
  const u16* gb[2]; int lb[2];
#pragma unroll
  for (int j = 0; j < 4; ++j) {
    const int L = j * 512 + tid;         // 2048 chunks: 256 rows x 8
    const int r = L >> 3;
    const int c = (L & 7) ^ (r & 7);
    la[j] = L * 16;
    ga[j] = A + (size_t)(m0 + r) * 1024 + c * 8;
  }
#pragma unroll
  for (int j = 0; j < 2; ++j) {
    const int L = j * 512 + tid;         // 1024 chunks: 128 rows x 8
    const int r = L >> 3;
    const int c = (L & 7) ^ (r & 7);
    lb[j] = L * 16;
    gb[j] = B + (size_t)(n0 + r) * 1024 + c * 8;
  }
  char* const sA0 = smem;                // buf b: A at b*49152, B at +32768

  // register fragment sets
  short8 bfr0[2][4], bfr1[2][4];         // B frags, double-buffered
  short8 a0f[2][2], a1f[2][2];           // A frags rows 0..31 / 32..63

  // prologue: stage tiles 0 and 1 (6 gloads each)
  {
    char* dA = sA0; char* dB = sA0 + 32768;
#pragma unroll
    for (int j = 0; j < 4; ++j) { gload16(ga[j], dA + la[j]); ga[j] += 64; }
#pragma unroll
    for (int j = 0; j < 2; ++j) { gload16(gb[j], dB + lb[j]); gb[j] += 64; }
    dA = sA0 + 49152; dB = dA + 32768;
#pragma unroll
    for (int j = 0; j < 4; ++j) { gload16(ga[j], dA + la[j]); ga[j] += 64; }
#pragma unroll
    for (int j = 0; j < 2; ++j) { gload16(gb[j], dB + lb[j]); gb[j] += 64; }
  }
  asm volatile("s_waitcnt vmcnt(6)" ::: "memory");   // tile0 done, tile1 in flight
  __builtin_amdgcn_s_barrier();
  asm volatile("" ::: "memory");
  // pre-read tile0's B + A0 frags (matches steady-state)
  {
    char* nA = sA0; char* nB = sA0 + 32768;
#pragma unroll
    for (int kk = 0; kk < 2; ++kk)
#pragma unroll
      for (int j = 0; j < 4; ++j) {
        const int rn = wc + j * 16 + l16;
        bfr0[kk][j] = *(const short8*)(nB + rn * 128 + (((kk << 2) + quad) ^ (rn & 7)) * 16);
      }
#pragma unroll
    for (int kk = 0; kk < 2; ++kk)
#pragma unroll
      for (int i = 0; i < 2; ++i) {
        const int rm = wr + i * 16 + l16;
        a0f[kk][i] = *(const short8*)(nA + rm * 128 + (((kk << 2) + quad) ^ (rm & 7)) * 16);
      }
  }

  int cur = 0;
  const int npair = (ntiles >> 1) - 1;   // staged tile-pairs
#pragma unroll 1
  for (int it = 0; it < npair; ++it) {   // tiles 0..ntiles-3 stage tiles 2..ntiles-1
    PTILE(bfr0, bfr1, true, 6, false);
    PTILE(bfr1, bfr0, true, 6, false);
  }
  PTILE(bfr0, bfr1, false, 0, false);    // tile ntiles-2: drain last tile's loads
  PTILE(bfr1, bfr0, false, 0, true);     // tile ntiles-1: last
  __syncthreads();                       // epilogue may rewrite LDS
}

#define ACC_ZERO4(acc) { _Pragma("unroll") for (int i=0;i<4;++i) \
  _Pragma("unroll") for (int j=0;j<4;++j) \
  _Pragma("unroll") for (int r=0;r<4;++r) acc[i][j][r]=0.f; }

// ---------- epilogue: 256x128 acc(+bias) -> bf16 C via LDS repack ----------
__device__ __forceinline__ void store256x128_bf16(
    f32x4 acc[4][4], const float* bias, int n0,
    u16* C, int m0, char* smem)
{
  const int tid = threadIdx.x, lane = tid & 63, wave = tid >> 6;
  const int quad = lane >> 4, l16 = lane & 15;
  const int wr = (wave >> 1) << 6, wc = (wave & 1) << 6;
  u16* t = (u16*)smem;                       // 256 x 136 u16
#pragma unroll
  for (int j = 0; j < 4; ++j) {
    const int nn = wc + j * 16 + l16;
    const float bj = bias[n0 + nn];
#pragma unroll
    for (int i = 0; i < 4; ++i) {
      const int mm = wr + i * 16 + quad * 4;
#pragma unroll
      for (int r = 0; r < 4; ++r)
        t[(mm + r) * 136 + nn] = f2bf(acc[i][j][r] + bj);
    }
  }
  __syncthreads();
#pragma unroll
  for (int it = 0; it < 8; ++it) {
    const int L = it * 512 + tid;              // 4096 chunks of 8 u16
    const int mm = L >> 4, cc = L & 15;
    *(uint4*)(C + (size_t)(m0 + mm) * 1024 + n0 + cc * 8) =
        *(const uint4*)(t + mm * 136 + cc * 8);
  }
}

// ---------- kernel 1: cast fp32 -> bf16 (x + 4 weights) + zero rowsum ----------
__global__ __launch_bounds__(256) void cast_inputs(
    const float* __restrict__ x,  const float* __restrict__ wq,
    const float* __restrict__ wk, const float* __restrict__ wv,
    const float* __restrict__ wo,
    u16* xb, u16* wqb, u16* wkb, u16* wvb, u16* wob, float* rsum)
{
  int b = blockIdx.x;
  if (b < 8) {                               // fold rowsum zeroing (8192 floats)
    float4 z = {0.f, 0.f, 0.f, 0.f};
    *(float4*)(rsum + (b * 256 + threadIdx.x) * 4) = z;
  }
  const float* src; u16* dst; int base;
  if (b < 4096) { src = x; dst = xb; base = b * 2048; }
  else {
    int r = (b - 4096) >> 9, bb = (b - 4096) & 511;
    base = bb * 2048;
    src = (r == 0) ? wq : (r == 1) ? wk : (r == 2) ? wv : wo;
    dst = (r == 0) ? wqb : (r == 1) ? wkb : (r == 2) ? wvb : wob;
  }
  int i0 = base + threadIdx.x * 8;
  float4 f0 = *(const float4*)(src + i0);
  float4 f1 = *(const float4*)(src + i0 + 4);
  short8 o;
  o[0]=(short)f2bf(f0.x); o[1]=(short)f2bf(f0.y); o[2]=(short)f2bf(f0.z); o[3]=(short)f2bf(f0.w);
  o[4]=(short)f2bf(f1.x); o[5]=(short)f2bf(f1.y); o[6]=(short)f2bf(f1.z); o[7]=(short)f2bf(f1.w);
  *(short8*)(dst + i0) = o;
}

// ---------- kernel 2: fused QKV projection, pipelined 256x128 core ----------
// grid (256, 3): x = XCD-chunked tile id, y = which weight (q/k/v).
__global__ __launch_bounds__(512, 2) void proj_qkv(
    const u16* __restrict__ xb,
    const u16* __restrict__ wqb, const u16* __restrict__ wkb, const u16* __restrict__ wvb,
    const float* __restrict__ bq, const float* __restrict__ bk, const float* __restrict__ bv,
    u16* q, u16* k, u16* vt)
{
  __shared__ char smem[147456];
  const int z = blockIdx.y;
  const u16* W = (z == 0) ? wqb : (z == 1) ? wkb : wvb;
  const float* bias = (z == 0) ? bq : (z == 1) ? bk : bv;
  const int id = blockIdx.x;                 // 0..255
  const int m0 = ((id & 7) * 4 + ((id >> 3) & 3)) * 256;   // XCD owns 4 m-tiles
  const int n0 = (id >> 5) * 128;

  f32x4 acc[4][4]; ACC_ZERO4(acc);
  gemm_256x128(xb, W, m0, n0, 16, smem, acc);

  if (z < 2) {
    store256x128_bf16(acc, bias, n0, (z == 0) ? q : k, m0, smem);
  } else {
    const int tid = threadIdx.x, lane = tid & 63, wave = tid >> 6;
    const int quad = lane >> 4, l16 = lane & 15;
    const int wr = (wave >> 1) << 6, wc = (wave & 1) << 6;
    u16* t = (u16*)smem;                     // transposed: t[n_local][m_local], 128 x 264
#pragma unroll
    for (int j = 0; j < 4; ++j) {
      const int nn = wc + j * 16 + l16;
      const float bj = bias[n0 + nn];
#pragma unroll
      for (int i = 0; i < 4; ++i) {
        const int mm = wr + i * 16 + quad * 4;
#pragma unroll
        for (int r = 0; r < 4; ++r)
          t[nn * 264 + mm + r] = f2bf(acc[i][j][r] + bj);
      }
    }
    __syncthreads();
    const int b = m0 >> 10, t0 = m0 & 1023;
#pragma unroll
    for (int it = 0; it < 8; ++it) {
      const int L = it * 512 + tid;          // 128 rows x 32 chunks of 8
      const int nn = L >> 5, cc = L & 31;
      *(uint4*)(vt + ((size_t)b << 20) + (size_t)(n0 + nn) * 1024 + t0 + cc * 8) =
          *(const uint4*)(t + nn * 264 + cc * 8);
    }
  }
}

// ---------- kernel 3: P' = exp(scale*QK^T), causal; 256x128 tiles ----------
// grid = 8 batches x 20 lower-triangle tiles (q-tile=256 rows, k-tile=128 cols)
__global__ __launch_bounds__(512, 2) void qk_exp256(
    const u16* __restrict__ q, const u16* __restrict__ k,
    u16* __restrict__ probs, float* __restrict__ rowsum)
{
  __shared__ char smem[147456];
  const int id = blockIdx.x;                 // 0..159
  const int b = id / 20;
  const int t = id - b * 20;
  // q-tile qi (256 rows) has 2*(qi+1) k-tiles; prefix 0,2,6,12
  const int qi = (t < 2) ? 0 : (t < 6) ? 1 : (t < 12) ? 2 : 3;
  const int pre = (qi == 0) ? 0 : (qi == 1) ? 2 : (qi == 2) ? 6 : 12;
  const int kt = t - pre;
  const int m0 = qi * 256, n0 = kt * 128;
  const u16* A = q + ((size_t)b << 20);
  const u16* B = k + ((size_t)b << 20);

  f32x4 acc[4][4]; ACC_ZERO4(acc);
  gemm_256x128(A, B, m0, n0, 16, smem, acc);

  const int tid = threadIdx.x, lane = tid & 63, wave = tid >> 6;
  const int quad = lane >> 4, l16 = lane & 15;
  const int wr = (wave >> 1) << 6, wc = (wave & 1) << 6;

  float part[4][4];
#pragma unroll
  for (int i = 0; i < 4; ++i)
#pragma unroll
    for (int r = 0; r < 4; ++r) part[i][r] = 0.f;

  u16* tl = (u16*)smem;                      // 256 x 136 u16 repack
#pragma unroll
  for (int j = 0; j < 4; ++j) {
    const int nn = wc + j * 16 + l16;
#pragma unroll
    for (int i = 0; i < 4; ++i) {
      const int mm = wr + i * 16 + quad * 4;
#pragma unroll
      for (int r = 0; r < 4; ++r) {
        float e = __expf(acc[i][j][r] * 0.03125f);
        if ((n0 + nn) > (m0 + mm + r)) e = 0.f; // causal (no-op for full tiles)
        part[i][r] += e;
        tl[(mm + r) * 136 + nn] = f2bf(e);
      }
    }
  }
  float* rs = rowsum + b * 1024 + m0;
#pragma unroll
  for (int i = 0; i < 4; ++i)
#pragma unroll
    for (int r = 0; r < 4; ++r) {
      float v = part[i][r];
      v += __shfl_xor(v, 1); v += __shfl_xor(v, 2);
      v += __shfl_xor(v, 4); v += __shfl_xor(v, 8);
      if (l16 == 0) atomicAdd(rs + wr + i * 16 + quad * 4 + r, v);
    }
  __syncthreads();
  u16* C = probs + ((size_t)b << 20);
#pragma unroll
  for (int it = 0; it < 8; ++it) {
    const int L = it * 512 + tid;            // 4096 chunks of 8 u16
    const int mm = L >> 4, cc = L & 15;
    *(uint4*)(C + (size_t)(m0 + mm) * 1024 + n0 + cc * 8) =
        *(const uint4*)(tl + mm * 136 + cc * 8);
  }
}

// ---------- kernel 4: O = diag(1/l) P' V; 256x128 tiles, variable K ----------
// grid = 256 blocks exactly: 8 batches x 4 q-tiles x 8 n-tiles
__global__ __launch_bounds__(512, 2) void pv256(
    const u16* __restrict__ probs, const u16* __restrict__ vt,
    const float* __restrict__ rowsum, u16* __restrict__ o)
{
  __shared__ char smem[147456];
  const int id = blockIdx.x;                 // 0..255
  const int b = id & 7;
  const int u = id >> 3;                     // 0..31
  const int qi = 3 - (u & 3);                // big-K blocks first
  const int nb = u >> 2;                     // 0..7
  const int m0 = qi * 256, n0 = nb * 128;
  const int nt = (qi + 1) * 4;               // K = (qi+1)*256, BK=64
  const u16* A = probs + ((size_t)b << 20);
  const u16* B = vt + ((size_t)b << 20);

  f32x4 acc[4][4]; ACC_ZERO4(acc);
  gemm_256x128(A, B, m0, n0, nt, smem, acc);

  const int tid = threadIdx.x, lane = tid & 63, wave = tid >> 6;
  const int quad = lane >> 4, l16 = lane & 15;
  const int wr = (wave >> 1) << 6, wc = (wave & 1) << 6;
  const float* rs = rowsum + b * 1024 + m0;
  u16* tl = (u16*)smem;                      // 256 x 136 u16
#pragma unroll
  for (int i = 0; i < 4; ++i)
#pragma unroll
    for (int r = 0; r < 4; ++r) {
      const int mm = wr + i * 16 + quad * 4 + r;
      const float inv = 1.0f / rs[mm];
#pragma unroll
      for (int j = 0; j < 4; ++j)
        tl[mm * 136 + wc + j * 16 + l16] = f2bf(acc[i][j][r] * inv);
    }
  __syncthreads();
  u16* C = o + ((size_t)b << 20);
#pragma unroll
  for (int it = 0; it < 8; ++it) {
    const int L = it * 512 + tid;
    const int mm = L >> 4, cc = L & 15;
    *(uint4*)(C + (size_t)(m0 + mm) * 1024 + n0 + cc * 8) =
        *(const uint4*)(tl + mm * 136 + cc * 8);
  }
}

// ---------- kernel 5: out = O Wo^T + bo; pipelined 256x128 core, fp32 epilogue ----------
__global__ __launch_bounds__(512, 2) void proj_o(
    const u16* __restrict__ ob, const u16* __restrict__ wob,
    const float* __restrict__ bo, float* __restrict__ out)
{
  __shared__ char smem[147456];
  const int id = blockIdx.x;                 // 0..255
  const int m0 = ((id & 7) * 4 + ((id >> 3) & 3)) * 256;
  const int n0 = (id >> 5) * 128;
  f32x4 acc[4][4]; ACC_ZERO4(acc);
  gemm_256x128(ob, wob, m0, n0, 16, smem, acc);

  const int tid = threadIdx.x, lane = tid & 63, wave = tid >> 6;
  const int quad = lane >> 4, l16 = lane & 15;
  const int wr = (wave >> 1) << 6, wc = (wave & 1) << 6;
  float* tf = (float*)smem;                  // 256 x 132 fp32
#pragma unroll
  for (int j = 0; j < 4; ++j) {
    const int nn = wc + j * 16 + l16;
    const float bj = bo[n0 + nn];
#pragma unroll
    for (int i = 0; i < 4; ++i)
#pragma unroll
      for (int r = 0; r < 4; ++r)
        tf[(wr + i * 16 + quad * 4 + r) * 132 + nn] = acc[i][j][r] + bj;
  }
  __syncthreads();
#pragma unroll
  for (int it = 0; it < 16; ++it) {
    const int L = it * 512 + tid;            // 256 rows x 32 float4
    const int mm = L >> 5, cc = L & 31;
    *(float4*)(out + (size_t)(m0 + mm) * 1024 + n0 + cc * 4) =
        *(const float4*)(tf + mm * 132 + cc * 4);
  }
}

// ---------- launch ----------
extern "C" void kernel_launch(void* const* d_in, const int* in_sizes, int n_in,
                              void* d_out, int out_size, void* d_ws, size_t ws_size,
                              hipStream_t stream) {
  const float* x  = (const float*)d_in[0];
  const float* wq = (const float*)d_in[1];
  const float* bq = (const float*)d_in[2];
  const float* wk = (const float*)d_in[3];
  const float* bk = (const float*)d_in[4];
  const float* wv = (const float*)d_in[5];
  const float* bv = (const float*)d_in[6];
  const float* wo = (const float*)d_in[7];
  const float* bo = (const float*)d_in[8];
  float* out = (float*)d_out;

  char* ws = (char*)d_ws;
  const size_t MB = 1u << 20;
  u16*  xb  = (u16*)(ws);            // 16 MB (x bf16; reused later as O bf16)
  u16*  wqb = (u16*)(ws + 16*MB);
  u16*  wkb = (u16*)(ws + 18*MB);
  u16*  wvb = (u16*)(ws + 20*MB);
  u16*  wob = (u16*)(ws + 22*MB);
  u16*  qb  = (u16*)(ws + 24*MB);
  u16*  kb  = (u16*)(ws + 40*MB);
  u16*  vtb = (u16*)(ws + 56*MB);    // V transposed per batch
  u16*  pr  = (u16*)(ws + 72*MB);    // bf16 unnormalized probs P'
  float* rsum = (float*)(ws + 88*MB);// 32 KB row sums

  cast_inputs<<<6144, 256, 0, stream>>>(x, wq, wk, wv, wo, xb, wqb, wkb, wvb, wob, rsum);
  proj_qkv<<<dim3(256, 3), 512, 0, stream>>>(xb, wqb, wkb, wvb, bq, bk, bv, qb, kb, vtb);
  qk_exp256<<<160, 512, 0, stream>>>(qb, kb, pr, rsum);
  pv256<<<256, 512, 0, stream>>>(pr, vtb, rsum, xb /* O reuses x region */);
  proj_o<<<256, 512, 0, stream>>>(xb, wob, bo, out);
}